// Round 9
// baseline (230.541 us; speedup 1.0000x reference)
//
#include <hip/hip_runtime.h>
#include <cstdint>
#include <cstddef>

#define MB_   4096
#define NK_   8
#define DM_   1024
#define DT_   128

typedef __bf16 bf16;
typedef __bf16 bf16x8 __attribute__((ext_vector_type(8)));
typedef __bf16 bf16x4 __attribute__((ext_vector_type(4)));
typedef float  f32x4  __attribute__((ext_vector_type(4)));

__device__ __forceinline__ void gload_lds16(const void* g, void* l) {
  __builtin_amdgcn_global_load_lds(
      (__attribute__((address_space(1))) void*)g,
      (__attribute__((address_space(3))) void*)l,
      16, 0, 0);
}

// chunk swizzle: logical 16B-chunk c of row r lives at LDS chunk c ^ hsw(r).
__device__ __forceinline__ int hsw(int r) { return (r ^ (r >> 2)) & 3; }

// ---------------------------------------------------------------------------
// merged prep: blocks [0,8192): proj_w f32->bf16; [8192,12288): w_vs transpose
__global__ void prep_kernel(const float* __restrict__ pw, bf16* __restrict__ pwb,
                            const float* __restrict__ wvs, bf16* __restrict__ wvt) {
  int b = blockIdx.x;
  if (b < 8192) {
    size_t i = ((size_t)b * 256 + threadIdx.x) * 4;
    float4 f = *(const float4*)&pw[i];
    bf16x4 o = { (bf16)f.x, (bf16)f.y, (bf16)f.z, (bf16)f.w };
    *(bf16x4*)&pwb[i] = o;
  } else {
    int o = (b - 8192) * 256 + threadIdx.x;
    int d = o & 1023;
    int t = (o >> 10) & 127;
    int n = o >> 17;
    wvt[o] = (bf16)wvs[(size_t)n * 131072 + (size_t)d * 128 + t];
  }
}

// ---------------------------------------------------------------------------
// GEMM1: v_s[n] = V_n[4096x1024](f32) @ WvT[n][128x1024]^T -> A2 scatter (bf16)
// VB: also emit vb16 = bf16(v) flat copy (residual for LN).
template<bool VB>
__global__ __launch_bounds__(256, 2) void gemm1_kernel(
    const float* __restrict__ vflat, const bf16* __restrict__ WvT,
    bf16* __restrict__ A2, bf16* __restrict__ vb)
{
  __shared__ __align__(16) bf16 As[64 * 32];
  __shared__ __align__(16) bf16 Bs[128 * 32];
  const int tid  = threadIdx.x;
  const int wave = tid >> 6, lane = tid & 63;
  const int wm = wave >> 1, wn = wave & 1;
  const int n  = blockIdx.y;
  const int b0 = blockIdx.x * 64;

  const int r  = tid >> 2;
  const int hr = hsw(r);
  const int cs = (tid & 3) ^ hr;

  const size_t vbase = ((size_t)(n * MB_ + b0 + r)) * 1024 + (tid & 3) * 8;
  const float* ag = vflat + vbase;
  bf16* awr = As + r * 32 + cs * 8;
  const bf16* bg = WvT + (size_t)n * 131072 + (size_t)r * 1024 + cs * 8;
  char* bsb = (char*)Bs + wave * 1024;

  f32x4 acc[2][4] = {};
  const int krow = lane & 15;
  const int cch  = lane >> 4;
  const int swoff = ((cch ^ hsw(krow)) << 4);

  for (int kt = 0; kt < 32; ++kt) {
    const bf16* bptr = bg + kt * 32;
    gload_lds16(bptr,             bsb);
    gload_lds16(bptr + 64 * 1024, bsb + 4096);
    const float* aptr = ag + kt * 32;
    float4 f0 = *(const float4*)(aptr + 0);
    float4 f1 = *(const float4*)(aptr + 4);
    bf16x8 h0 = { (bf16)f0.x, (bf16)f0.y, (bf16)f0.z, (bf16)f0.w,
                  (bf16)f1.x, (bf16)f1.y, (bf16)f1.z, (bf16)f1.w };
    *(bf16x8*)awr = h0;
    if (VB) *(bf16x8*)&vb[vbase + kt * 32] = h0;
    __syncthreads();

    bf16x8 af[2], bfr[4];
    #pragma unroll
    for (int i = 0; i < 2; ++i)
      af[i] = *(const bf16x8*)((const char*)As + (wm * 32 + i * 16 + krow) * 64 + swoff);
    #pragma unroll
    for (int j = 0; j < 4; ++j)
      bfr[j] = *(const bf16x8*)((const char*)Bs + (wn * 64 + j * 16 + krow) * 64 + swoff);
    #pragma unroll
    for (int i = 0; i < 2; ++i)
      #pragma unroll
      for (int j = 0; j < 4; ++j)
        acc[i][j] = __builtin_amdgcn_mfma_f32_16x16x32_bf16(af[i], bfr[j], acc[i][j], 0, 0, 0);
    __syncthreads();
  }

  #pragma unroll
  for (int i = 0; i < 2; ++i) {
    #pragma unroll
    for (int j = 0; j < 4; ++j) {
      int t = wn * 64 + j * 16 + (lane & 15);
      #pragma unroll
      for (int rr = 0; rr < 4; ++rr) {
        int b = b0 + wm * 32 + i * 16 + (lane >> 4) * 4 + rr;
        size_t off = ((size_t)(n * 512 + (b >> 3))) * 1024 + (size_t)(b & 7) * 128 + t;
        A2[off] = (bf16)acc[i][j][rr];
      }
    }
  }
}

// ---------------------------------------------------------------------------
// GEMM2: x[4096][8192] = A2 @ PW^T + pb. 128x128 tile, BK=32, 4 waves,
// 3 LDS buffers (48KB -> 3 blocks/CU), 2-ahead staging, counted vmcnt(4),
// raw barrier + lgkmcnt(0) boundary only; interior compiler-scheduled.
template<bool ZB>
__global__ __launch_bounds__(256, 3) void gemm2k_kernel(
    const bf16* __restrict__ A2, const bf16* __restrict__ PW,
    const float* __restrict__ pb, void* __restrict__ xoutp)
{
  __shared__ __align__(16) bf16 As[3][4096];  // 8KB per buf (128 rows x 32 k)
  __shared__ __align__(16) bf16 Bs[3][4096];

  const int tid  = threadIdx.x;
  const int wave = tid >> 6, lane = tid & 63;
  const int wm = wave >> 1, wn = wave & 1;

  // XCD swizzle: XCD x owns a contiguous 8-wide n strip (PW 2MB -> L2 fit).
  const int bid   = blockIdx.x;          // 0..2047
  const int x     = bid & 7;
  const int local = bid >> 3;            // 0..255
  const int mt    = local & 31;
  const int nt    = x * 8 + (local >> 5);
  const int m0    = mt * 128;
  const int n0    = nt * 128;

  // staging: thread stages chunk (tid&3)^hsw(row) of rows (tid>>2) and +64
  const int rS = tid >> 2;
  const int cS = (tid & 3) ^ hsw(rS);
  const bf16* aG0 = A2 + (size_t)(m0 + rS) * 1024 + cS * 8;
  const bf16* aG1 = aG0 + (size_t)64 * 1024;
  const bf16* bG0 = PW + (size_t)(n0 + rS) * 1024 + cS * 8;
  const bf16* bG1 = bG0 + (size_t)64 * 1024;
  char* const ldsA = (char*)As[0] + wave * 1024;   // wave-uniform dest bases
  char* const ldsB = (char*)Bs[0] + wave * 1024;

  #define STAGE(t, bi) { char* dA = ldsA + (bi) * 8192;                      \
                         char* dB = ldsB + (bi) * 8192;                      \
                         gload_lds16(aG0 + (size_t)(t) * 32, dA);            \
                         gload_lds16(aG1 + (size_t)(t) * 32, dA + 4096);     \
                         gload_lds16(bG0 + (size_t)(t) * 32, dB);            \
                         gload_lds16(bG1 + (size_t)(t) * 32, dB + 4096); }

  // prologue: stage sub-tiles 0,1; wait tile 0 (4 in flight for tile 1)
  STAGE(0, 0); STAGE(1, 1);
  asm volatile("s_waitcnt vmcnt(4)" ::: "memory");
  __builtin_amdgcn_s_barrier();
  __builtin_amdgcn_sched_barrier(0);

  f32x4 acc[4][4] = {};
  const int krow = lane & 15;
  const int cch  = lane >> 4;
  const int swoff = ((cch ^ hsw(krow)) << 4);

  int rd = 0;                         // buf index of sub-tile s
  #pragma unroll 1
  for (int s = 0; s < 32; ++s) {
    const int st = rd >= 1 ? rd - 1 : 2;   // (s+2)%3
    if (s < 30) STAGE(s + 2, st);

    const char* pA = (const char*)As[rd];
    const char* pB = (const char*)Bs[rd];
    bf16x8 af[4], bfr[4];
    #pragma unroll
    for (int i = 0; i < 4; ++i)
      af[i] = *(const bf16x8*)(pA + (wm * 64 + i * 16 + krow) * 64 + swoff);
    #pragma unroll
    for (int j = 0; j < 4; ++j)
      bfr[j] = *(const bf16x8*)(pB + (wn * 64 + j * 16 + krow) * 64 + swoff);
    #pragma unroll
    for (int i = 0; i < 4; ++i)
      #pragma unroll
      for (int j = 0; j < 4; ++j)
        acc[i][j] = __builtin_amdgcn_mfma_f32_16x16x32_bf16(af[i], bfr[j], acc[i][j], 0, 0, 0);

    if (s < 31) {
      asm volatile("s_waitcnt lgkmcnt(0)" ::: "memory");
      if (s < 30)       { asm volatile("s_waitcnt vmcnt(4)" ::: "memory"); }
      else              { asm volatile("s_waitcnt vmcnt(0)" ::: "memory"); }
      __builtin_amdgcn_s_barrier();
      __builtin_amdgcn_sched_barrier(0);
    }
    rd = rd >= 2 ? 0 : rd + 1;
  }
  #undef STAGE

  // epilogue: x = acc + pb -> bf16 ws (or f32 d_out)
  #pragma unroll
  for (int i = 0; i < 4; ++i) {
    #pragma unroll
    for (int j = 0; j < 4; ++j) {
      int nn = n0 + wn * 64 + j * 16 + krow;
      float pbn = pb[nn];
      #pragma unroll
      for (int r = 0; r < 4; ++r) {
        int mm = m0 + wm * 64 + i * 16 + cch * 4 + r;
        size_t off = (size_t)mm * 8192 + nn;
        float val = acc[i][j][r] + pbn;
        if (ZB) ((bf16*)xoutp)[off] = (bf16)val;
        else    ((float*)xoutp)[off] = val;
      }
    }
  }
}

// ---------------------------------------------------------------------------
// LN over 1024-wide rows: x = z + v(residual); ddof=1, eps outside sqrt.
// VB: residual from bf16 copy; else f32 v. Also fills attns (first 128 blocks).
template<bool ZB, bool VB>
__global__ __launch_bounds__(256) void ln_kernel(
    const void* zin, const float* __restrict__ vres, const bf16* __restrict__ vb,
    const float* __restrict__ gamma, const float* __restrict__ beta,
    float* outp)
{
  __shared__ float red[16];
  const int row = blockIdx.x;
  const int tid = threadIdx.x;
  if (row < 128) outp[(size_t)33554432 + row * 256 + tid] = 1.0f;
  const size_t base = (size_t)row * 1024 + tid * 4;

  float4 rv;
  if (VB) {
    bf16x4 vb4 = *(const bf16x4*)(vb + base);
    rv.x = (float)vb4[0]; rv.y = (float)vb4[1]; rv.z = (float)vb4[2]; rv.w = (float)vb4[3];
  } else {
    rv = *(const float4*)&vres[base];
  }
  float4 x;
  if (ZB) {
    bf16x4 zb4 = *(const bf16x4*)((const bf16*)zin + base);
    x.x = (float)zb4[0] + rv.x; x.y = (float)zb4[1] + rv.y;
    x.z = (float)zb4[2] + rv.z; x.w = (float)zb4[3] + rv.w;
  } else {
    float4 zf = *(const float4*)((const float*)zin + base);
    x.x = zf.x + rv.x; x.y = zf.y + rv.y; x.z = zf.z + rv.z; x.w = zf.w + rv.w;
  }

  float s  = x.x + x.y + x.z + x.w;
  float ss = x.x * x.x + x.y * x.y + x.z * x.z + x.w * x.w;
  #pragma unroll
  for (int m = 32; m >= 1; m >>= 1) {
    s  += __shfl_xor(s,  m, 64);
    ss += __shfl_xor(ss, m, 64);
  }
  const int wave = tid >> 6, lane = tid & 63;
  if (lane == 0) { red[wave] = s; red[wave + 8] = ss; }
  __syncthreads();
  float S  = red[0] + red[1] + red[2] + red[3];
  float SS = red[8] + red[9] + red[10] + red[11];
  float mu  = S * (1.0f / 1024.0f);
  float var = (SS - 1024.0f * mu * mu) * (1.0f / 1023.0f);
  var = var < 0.0f ? 0.0f : var;
  float rs = 1.0f / (sqrtf(var) + 1e-3f);
  float4 gmv = *(const float4*)&gamma[tid * 4];
  float4 be  = *(const float4*)&beta[tid * 4];
  float4 y;
  y.x = (x.x - mu) * rs * gmv.x + be.x;
  y.y = (x.y - mu) * rs * gmv.y + be.y;
  y.z = (x.z - mu) * rs * gmv.z + be.z;
  y.w = (x.w - mu) * rs * gmv.w + be.w;
  *(float4*)&outp[base] = y;
}

// ---------------------------------------------------------------------------
extern "C" void kernel_launch(void* const* d_in, const int* in_sizes, int n_in,
                              void* d_out, int out_size, void* d_ws, size_t ws_size,
                              hipStream_t stream) {
  const float* v     = (const float*)d_in[2];
  const float* wvs   = (const float*)d_in[5];
  const float* pw    = (const float*)d_in[6];
  const float* pb    = (const float*)d_in[7];
  const float* gamma = (const float*)d_in[8];
  const float* beta  = (const float*)d_in[9];
  float* out = (float*)d_out;

  // ws: PW bf16 16M | WvT bf16 2M | A2 bf16 8M | x bf16 64M | vb bf16 64M
  const size_t OFF_WVT = 16777216;
  const size_t OFF_A2  = OFF_WVT + 2097152;
  const size_t OFF_X   = OFF_A2 + 8388608;
  const size_t OFF_VB  = OFF_X + 67108864;
  const size_t NEED_ZB = OFF_VB;                    // x fits
  const size_t NEED_VB = OFF_VB + 67108864;         // + vb16 copy

  bf16* PWb = (bf16*)d_ws;
  bf16* WvT = (bf16*)((char*)d_ws + OFF_WVT);
  bf16* A2  = (bf16*)((char*)d_ws + OFF_A2);
  bf16* VB16= (bf16*)((char*)d_ws + OFF_VB);
  const bool zb = (ws_size >= NEED_ZB);
  const bool vbe = (ws_size >= NEED_VB);
  void* xbuf = zb ? (void*)((char*)d_ws + OFF_X) : (void*)out;

  hipLaunchKernelGGL(prep_kernel, dim3(12288), dim3(256), 0, stream, pw, PWb, wvs, WvT);
  if (vbe)
    hipLaunchKernelGGL((gemm1_kernel<true>),  dim3(64, 8), dim3(256), 0, stream, v, WvT, A2, VB16);
  else
    hipLaunchKernelGGL((gemm1_kernel<false>), dim3(64, 8), dim3(256), 0, stream, v, WvT, A2, VB16);

  if (zb) {
    hipLaunchKernelGGL((gemm2k_kernel<true>),  dim3(2048), dim3(256), 0, stream, A2, PWb, pb, xbuf);
    if (vbe)
      hipLaunchKernelGGL((ln_kernel<true, true>),  dim3(32768), dim3(256), 0, stream, xbuf, v, VB16, gamma, beta, out);
    else
      hipLaunchKernelGGL((ln_kernel<true, false>), dim3(32768), dim3(256), 0, stream, xbuf, v, VB16, gamma, beta, out);
  } else {
    hipLaunchKernelGGL((gemm2k_kernel<false>), dim3(2048), dim3(256), 0, stream, A2, PWb, pb, xbuf);
    hipLaunchKernelGGL((ln_kernel<false, false>), dim3(32768), dim3(256), 0, stream, xbuf, v, VB16, gamma, beta, out);
  }
}

// Round 10
// 202.213 us; speedup vs baseline: 1.1401x; 1.1401x over previous
//
#include <hip/hip_runtime.h>
#include <cstdint>
#include <cstddef>

#define MB_   4096
#define NK_   8
#define DM_   1024
#define DT_   128

typedef __bf16 bf16;
typedef __bf16 bf16x8 __attribute__((ext_vector_type(8)));
typedef __bf16 bf16x4 __attribute__((ext_vector_type(4)));
typedef float  f32x4  __attribute__((ext_vector_type(4)));

__device__ __forceinline__ void gload_lds16(const void* g, void* l) {
  __builtin_amdgcn_global_load_lds(
      (__attribute__((address_space(1))) void*)g,
      (__attribute__((address_space(3))) void*)l,
      16, 0, 0);
}

// chunk swizzle: logical 16B-chunk c of row r lives at LDS chunk c ^ hsw(r).
__device__ __forceinline__ int hsw(int r) { return (r ^ (r >> 2)) & 3; }

// ---------------------------------------------------------------------------
// merged prep: blocks [0,8192): proj_w f32->bf16; [8192,12288): w_vs transpose
__global__ void prep_kernel(const float* __restrict__ pw, bf16* __restrict__ pwb,
                            const float* __restrict__ wvs, bf16* __restrict__ wvt) {
  int b = blockIdx.x;
  if (b < 8192) {
    size_t i = ((size_t)b * 256 + threadIdx.x) * 4;
    float4 f = *(const float4*)&pw[i];
    bf16x4 o = { (bf16)f.x, (bf16)f.y, (bf16)f.z, (bf16)f.w };
    *(bf16x4*)&pwb[i] = o;
  } else {
    int o = (b - 8192) * 256 + threadIdx.x;
    int d = o & 1023;
    int t = (o >> 10) & 127;
    int n = o >> 17;
    wvt[o] = (bf16)wvs[(size_t)n * 131072 + (size_t)d * 128 + t];
  }
}

// ---------------------------------------------------------------------------
// GEMM1: v_s[n] = V_n[4096x1024](f32) @ WvT[n][128x1024]^T -> A2 scatter (bf16)
__global__ __launch_bounds__(256, 2) void gemm1_kernel(
    const float* __restrict__ vflat, const bf16* __restrict__ WvT,
    bf16* __restrict__ A2)
{
  __shared__ __align__(16) bf16 As[64 * 32];
  __shared__ __align__(16) bf16 Bs[128 * 32];
  const int tid  = threadIdx.x;
  const int wave = tid >> 6, lane = tid & 63;
  const int wm = wave >> 1, wn = wave & 1;
  const int n  = blockIdx.y;
  const int b0 = blockIdx.x * 64;

  const int r  = tid >> 2;
  const int hr = hsw(r);
  const int cs = (tid & 3) ^ hr;

  const float* ag = vflat + ((size_t)(n * MB_ + b0 + r)) * 1024 + (tid & 3) * 8;
  bf16* awr = As + r * 32 + cs * 8;
  const bf16* bg = WvT + (size_t)n * 131072 + (size_t)r * 1024 + cs * 8;
  char* bsb = (char*)Bs + wave * 1024;

  f32x4 acc[2][4] = {};
  const int krow = lane & 15;
  const int cch  = lane >> 4;
  const int swoff = ((cch ^ hsw(krow)) << 4);

  for (int kt = 0; kt < 32; ++kt) {
    const bf16* bptr = bg + kt * 32;
    gload_lds16(bptr,             bsb);
    gload_lds16(bptr + 64 * 1024, bsb + 4096);
    const float* aptr = ag + kt * 32;
    float4 f0 = *(const float4*)(aptr + 0);
    float4 f1 = *(const float4*)(aptr + 4);
    bf16x8 h0 = { (bf16)f0.x, (bf16)f0.y, (bf16)f0.z, (bf16)f0.w,
                  (bf16)f1.x, (bf16)f1.y, (bf16)f1.z, (bf16)f1.w };
    *(bf16x8*)awr = h0;
    __syncthreads();

    bf16x8 af[2], bfr[4];
    #pragma unroll
    for (int i = 0; i < 2; ++i)
      af[i] = *(const bf16x8*)((const char*)As + (wm * 32 + i * 16 + krow) * 64 + swoff);
    #pragma unroll
    for (int j = 0; j < 4; ++j)
      bfr[j] = *(const bf16x8*)((const char*)Bs + (wn * 64 + j * 16 + krow) * 64 + swoff);
    #pragma unroll
    for (int i = 0; i < 2; ++i)
      #pragma unroll
      for (int j = 0; j < 4; ++j)
        acc[i][j] = __builtin_amdgcn_mfma_f32_16x16x32_bf16(af[i], bfr[j], acc[i][j], 0, 0, 0);
    __syncthreads();
  }

  #pragma unroll
  for (int i = 0; i < 2; ++i) {
    #pragma unroll
    for (int j = 0; j < 4; ++j) {
      int t = wn * 64 + j * 16 + (lane & 15);
      #pragma unroll
      for (int rr = 0; rr < 4; ++rr) {
        int b = b0 + wm * 32 + i * 16 + (lane >> 4) * 4 + rr;
        size_t off = ((size_t)(n * 512 + (b >> 3))) * 1024 + (size_t)(b & 7) * 128 + t;
        A2[off] = (bf16)acc[i][j][rr];
      }
    }
  }
}

// ---------------------------------------------------------------------------
// GEMM2 (round-4 proven schedule) + fused v/bias/x-write/stats epilogue.
// x = A2 @ PW^T + pb + v -> bf16 ws (or f32 d_out); per-row partial (S,SS)
// over this tile's n-quarter -> stats[lnrow][quarter].
// Tile 256x256, BK=32, 4 LDS buffers, 2-deep staging, counted vmcnt(4).
template<bool ZB>
__global__ __launch_bounds__(512, 2) void gemm2pv_kernel(
    const bf16* __restrict__ A2, const bf16* __restrict__ PW,
    const float* __restrict__ vres, const float* __restrict__ pb,
    void* __restrict__ xoutp, float2* __restrict__ stats)
{
  __shared__ __align__(16) bf16 As[4][8192];  // [buf][256*32]
  __shared__ __align__(16) bf16 Bs[4][8192];

  const int tid  = threadIdx.x;
  const int w    = tid >> 6;
  const int lane = tid & 63;
  const int wm   = w >> 2;       // 0..1
  const int wn   = w & 3;        // 0..3

  const int bid   = blockIdx.x;          // 0..511
  const int x     = bid & 7;
  const int local = bid >> 3;            // 0..63
  const int mt    = local & 15;
  const int nt    = x * 4 + (local >> 4);
  const int m0    = mt * 256;
  const int n0    = nt * 256;

  const int rS = tid >> 2;
  const int cS = (tid & 3) ^ hsw(rS);
  const char* aG0 = (const char*)A2 + (size_t)(m0 + rS) * 2048 + cS * 16;
  const char* aG1 = aG0 + (size_t)128 * 2048;
  const char* bG0 = (const char*)PW + (size_t)(n0 + rS) * 2048 + cS * 16;
  const char* bG1 = bG0 + (size_t)128 * 2048;

  #define STAGE_A(t) { char* d = (char*)As[(t) & 3] + tid * 16;            \
                       gload_lds16(aG0 + (t) * 64, d);                      \
                       gload_lds16(aG1 + (t) * 64, d + 8192); }
  #define STAGE_B(t) { char* d = (char*)Bs[(t) & 3] + tid * 16;            \
                       gload_lds16(bG0 + (t) * 64, d);                      \
                       gload_lds16(bG1 + (t) * 64, d + 8192); }

  STAGE_A(0); STAGE_B(0); STAGE_A(1); STAGE_B(1);
  asm volatile("s_waitcnt vmcnt(4)" ::: "memory");
  __builtin_amdgcn_sched_barrier(0);
  __builtin_amdgcn_s_barrier();

  f32x4 acc[8][4] = {};
  const int fr = lane & 15;
  const int g  = lane >> 4;
  const int swoff = ((g ^ hsw(fr)) << 4);
  const int aRd = (wm * 128 + fr) * 64 + swoff;
  const int bRd = (wn * 64  + fr) * 64 + swoff;

  #pragma unroll 4
  for (int t = 0; t < 32; ++t) {
    const char* pA = (const char*)As[t & 3] + aRd;
    const char* pB = (const char*)Bs[t & 3] + bRd;

    // ---- phase 1 ----
    bf16x8 a[4], b[4];
    #pragma unroll
    for (int m = 0; m < 4; ++m) a[m] = *(const bf16x8*)(pA + m * 1024);
    #pragma unroll
    for (int n = 0; n < 4; ++n) b[n] = *(const bf16x8*)(pB + n * 1024);
    if (t < 30) STAGE_A(t + 2);
    __builtin_amdgcn_s_barrier();
    __builtin_amdgcn_s_setprio(1);
    #pragma unroll
    for (int m = 0; m < 4; ++m)
      #pragma unroll
      for (int n = 0; n < 4; ++n)
        acc[m][n] = __builtin_amdgcn_mfma_f32_16x16x32_bf16(a[m], b[n], acc[m][n], 0, 0, 0);
    __builtin_amdgcn_s_setprio(0);
    __builtin_amdgcn_s_barrier();

    // ---- phase 2 ----
    bf16x8 a2[4];
    #pragma unroll
    for (int m = 0; m < 4; ++m) a2[m] = *(const bf16x8*)(pA + (4 + m) * 1024);
    if (t < 30) STAGE_B(t + 2);
    __builtin_amdgcn_s_barrier();
    __builtin_amdgcn_s_setprio(1);
    #pragma unroll
    for (int m = 0; m < 4; ++m)
      #pragma unroll
      for (int n = 0; n < 4; ++n)
        acc[4 + m][n] = __builtin_amdgcn_mfma_f32_16x16x32_bf16(a2[m], b[n], acc[4 + m][n], 0, 0, 0);
    __builtin_amdgcn_s_setprio(0);
    if (t < 30)       { asm volatile("s_waitcnt vmcnt(4)" ::: "memory"); }
    else if (t == 30) { asm volatile("s_waitcnt vmcnt(0)" ::: "memory"); }
    __builtin_amdgcn_sched_barrier(0);
    __builtin_amdgcn_s_barrier();
  }
  #undef STAGE_A
  #undef STAGE_B

  // ---- epilogue: x = acc + pb + v; write x; per-row partial stats ----
  float pbv[4];
  #pragma unroll
  for (int n = 0; n < 4; ++n) pbv[n] = pb[n0 + wn * 64 + n * 16 + fr];

  float* sredS = (float*)&As[0][0];   // 256 rows x 4 wn
  float* sredQ = sredS + 1024;

  const float* vb0 = vres + (size_t)(m0 + wm * 128 + g * 4) * 8192 + (n0 + wn * 64 + fr);

  #pragma unroll
  for (int m = 0; m < 8; ++m) {
    #pragma unroll
    for (int r = 0; r < 4; ++r) {
      const float* vrow = vb0 + (size_t)(m * 16 + r) * 8192;
      float xv[4];
      float s = 0.0f, q2 = 0.0f;
      #pragma unroll
      for (int n = 0; n < 4; ++n) {
        xv[n] = acc[m][n][r] + pbv[n] + vrow[n * 16];
        s += xv[n]; q2 += xv[n] * xv[n];
      }
      size_t ro = (size_t)(m0 + wm * 128 + m * 16 + g * 4 + r) * 8192 + (n0 + wn * 64 + fr);
      #pragma unroll
      for (int n = 0; n < 4; ++n) {
        if (ZB) ((bf16*)xoutp)[ro + n * 16] = (bf16)xv[n];
        else    ((float*)xoutp)[ro + n * 16] = xv[n];
      }
      #pragma unroll
      for (int msk = 8; msk >= 1; msk >>= 1) {
        s  += __shfl_xor(s,  msk, 64);
        q2 += __shfl_xor(q2, msk, 64);
      }
      if (fr == 0) {
        int lrow = wm * 128 + m * 16 + g * 4 + r;
        sredS[lrow * 4 + wn] = s;
        sredQ[lrow * 4 + wn] = q2;
      }
    }
  }
  __syncthreads();
  if (tid < 256) {
    float S  = sredS[tid * 4] + sredS[tid * 4 + 1] + sredS[tid * 4 + 2] + sredS[tid * 4 + 3];
    float SS = sredQ[tid * 4] + sredQ[tid * 4 + 1] + sredQ[tid * 4 + 2] + sredQ[tid * 4 + 3];
    int lnrow = (m0 + tid) * 8 + (n0 >> 10);
    stats[(size_t)lnrow * 4 + ((n0 >> 8) & 3)] = make_float2(S, SS);
  }
}

// ---------------------------------------------------------------------------
// LN apply: per LN row, read 4 quarter stats + x, write out. Fills attns too.
template<bool ZB>
__global__ __launch_bounds__(256) void ln_apply_kernel(
    const void* xin, const float2* __restrict__ stats,
    const float* __restrict__ gamma, const float* __restrict__ beta,
    float* outp)
{
  const int bid = blockIdx.x;          // 0..32767
  const int tid = threadIdx.x;
  if (bid < 128) outp[(size_t)33554432 + bid * 256 + tid] = 1.0f;

  float2 st0 = stats[(size_t)bid * 4 + 0];
  float2 st1 = stats[(size_t)bid * 4 + 1];
  float2 st2 = stats[(size_t)bid * 4 + 2];
  float2 st3 = stats[(size_t)bid * 4 + 3];
  float S  = st0.x + st1.x + st2.x + st3.x;
  float SS = st0.y + st1.y + st2.y + st3.y;
  float mu  = S * (1.0f / 1024.0f);
  float var = (SS - 1024.0f * mu * mu) * (1.0f / 1023.0f);
  var = var < 0.0f ? 0.0f : var;
  float rs = 1.0f / (sqrtf(var) + 1e-3f);

  const size_t base = (size_t)bid * 1024 + tid * 4;
  float4 xv;
  if (ZB) {
    bf16x4 xb = *(const bf16x4*)((const bf16*)xin + base);
    xv.x = (float)xb[0]; xv.y = (float)xb[1]; xv.z = (float)xb[2]; xv.w = (float)xb[3];
  } else {
    xv = *(const float4*)((const float*)xin + base);
  }
  float4 ga = *(const float4*)&gamma[tid * 4];
  float4 be = *(const float4*)&beta[tid * 4];
  float4 y;
  y.x = (xv.x - mu) * rs * ga.x + be.x;
  y.y = (xv.y - mu) * rs * ga.y + be.y;
  y.z = (xv.z - mu) * rs * ga.z + be.z;
  y.w = (xv.w - mu) * rs * ga.w + be.w;
  *(float4*)&outp[base] = y;
}

// ---------------------------------------------------------------------------
extern "C" void kernel_launch(void* const* d_in, const int* in_sizes, int n_in,
                              void* d_out, int out_size, void* d_ws, size_t ws_size,
                              hipStream_t stream) {
  const float* v     = (const float*)d_in[2];
  const float* wvs   = (const float*)d_in[5];
  const float* pw    = (const float*)d_in[6];
  const float* pb    = (const float*)d_in[7];
  const float* gamma = (const float*)d_in[8];
  const float* beta  = (const float*)d_in[9];
  float* out = (float*)d_out;

  // ws: PW bf16 16M | WvT bf16 2M | A2 bf16 8M | stats 1M | x bf16 64M
  const size_t OFF_WVT = 16777216;
  const size_t OFF_A2  = OFF_WVT + 2097152;
  const size_t OFF_ST  = OFF_A2 + 8388608;
  const size_t OFF_X   = OFF_ST + 1048576;
  const size_t NEED_ZB = OFF_X + 67108864;

  bf16*   PWb   = (bf16*)d_ws;
  bf16*   WvT   = (bf16*)((char*)d_ws + OFF_WVT);
  bf16*   A2    = (bf16*)((char*)d_ws + OFF_A2);
  float2* stats = (float2*)((char*)d_ws + OFF_ST);
  const bool zb = (ws_size >= NEED_ZB);
  void* xbuf = zb ? (void*)((char*)d_ws + OFF_X) : (void*)out;

  hipLaunchKernelGGL(prep_kernel, dim3(12288), dim3(256), 0, stream, pw, PWb, wvs, WvT);
  hipLaunchKernelGGL(gemm1_kernel, dim3(64, 8), dim3(256), 0, stream, v, WvT, A2);
  if (zb) {
    hipLaunchKernelGGL((gemm2pv_kernel<true>),  dim3(512), dim3(512), 0, stream,
                       A2, PWb, v, pb, xbuf, stats);
    hipLaunchKernelGGL((ln_apply_kernel<true>), dim3(32768), dim3(256), 0, stream,
                       xbuf, stats, gamma, beta, out);
  } else {
    hipLaunchKernelGGL((gemm2pv_kernel<false>), dim3(512), dim3(512), 0, stream,
                       A2, PWb, v, pb, xbuf, stats);
    hipLaunchKernelGGL((ln_apply_kernel<false>), dim3(32768), dim3(256), 0, stream,
                       xbuf, stats, gamma, beta, out);
  }
}

// Round 11
// 197.870 us; speedup vs baseline: 1.1651x; 1.0220x over previous
//
#include <hip/hip_runtime.h>
#include <cstdint>
#include <cstddef>

#define MB_   4096
#define NK_   8
#define DM_   1024
#define DT_   128

typedef __bf16 bf16;
typedef __bf16 bf16x8 __attribute__((ext_vector_type(8)));
typedef __bf16 bf16x4 __attribute__((ext_vector_type(4)));
typedef float  f32x4  __attribute__((ext_vector_type(4)));

__device__ __forceinline__ void gload_lds16(const void* g, void* l) {
  __builtin_amdgcn_global_load_lds(
      (__attribute__((address_space(1))) void*)g,
      (__attribute__((address_space(3))) void*)l,
      16, 0, 0);
}

// chunk swizzle: logical 16B-chunk c of row r lives at LDS chunk c ^ hsw(r).
__device__ __forceinline__ int hsw(int r) { return (r ^ (r >> 2)) & 3; }

// ---------------------------------------------------------------------------
// merged prep: blocks [0,8192): proj_w f32->bf16; [8192,12288): w_vs transpose
__global__ void prep_kernel(const float* __restrict__ pw, bf16* __restrict__ pwb,
                            const float* __restrict__ wvs, bf16* __restrict__ wvt) {
  int b = blockIdx.x;
  if (b < 8192) {
    size_t i = ((size_t)b * 256 + threadIdx.x) * 4;
    float4 f = *(const float4*)&pw[i];
    bf16x4 o = { (bf16)f.x, (bf16)f.y, (bf16)f.z, (bf16)f.w };
    *(bf16x4*)&pwb[i] = o;
  } else {
    int o = (b - 8192) * 256 + threadIdx.x;
    int d = o & 1023;
    int t = (o >> 10) & 127;
    int n = o >> 17;
    wvt[o] = (bf16)wvs[(size_t)n * 131072 + (size_t)d * 128 + t];
  }
}

// ---------------------------------------------------------------------------
// GEMM1: v_s[n] = V_n[4096x1024](f32) @ WvT[n][128x1024]^T -> A2 scatter (bf16)
__global__ __launch_bounds__(256, 2) void gemm1_kernel(
    const float* __restrict__ vflat, const bf16* __restrict__ WvT,
    bf16* __restrict__ A2)
{
  __shared__ __align__(16) bf16 As[64 * 32];
  __shared__ __align__(16) bf16 Bs[128 * 32];
  const int tid  = threadIdx.x;
  const int wave = tid >> 6, lane = tid & 63;
  const int wm = wave >> 1, wn = wave & 1;
  const int n  = blockIdx.y;
  const int b0 = blockIdx.x * 64;

  const int r  = tid >> 2;
  const int hr = hsw(r);
  const int cs = (tid & 3) ^ hr;

  const float* ag = vflat + ((size_t)(n * MB_ + b0 + r)) * 1024 + (tid & 3) * 8;
  bf16* awr = As + r * 32 + cs * 8;
  const bf16* bg = WvT + (size_t)n * 131072 + (size_t)r * 1024 + cs * 8;
  char* bsb = (char*)Bs + wave * 1024;

  f32x4 acc[2][4] = {};
  const int krow = lane & 15;
  const int cch  = lane >> 4;
  const int swoff = ((cch ^ hsw(krow)) << 4);

  for (int kt = 0; kt < 32; ++kt) {
    const bf16* bptr = bg + kt * 32;
    gload_lds16(bptr,             bsb);
    gload_lds16(bptr + 64 * 1024, bsb + 4096);
    const float* aptr = ag + kt * 32;
    float4 f0 = *(const float4*)(aptr + 0);
    float4 f1 = *(const float4*)(aptr + 4);
    bf16x8 h0 = { (bf16)f0.x, (bf16)f0.y, (bf16)f0.z, (bf16)f0.w,
                  (bf16)f1.x, (bf16)f1.y, (bf16)f1.z, (bf16)f1.w };
    *(bf16x8*)awr = h0;
    __syncthreads();

    bf16x8 af[2], bfr[4];
    #pragma unroll
    for (int i = 0; i < 2; ++i)
      af[i] = *(const bf16x8*)((const char*)As + (wm * 32 + i * 16 + krow) * 64 + swoff);
    #pragma unroll
    for (int j = 0; j < 4; ++j)
      bfr[j] = *(const bf16x8*)((const char*)Bs + (wn * 64 + j * 16 + krow) * 64 + swoff);
    #pragma unroll
    for (int i = 0; i < 2; ++i)
      #pragma unroll
      for (int j = 0; j < 4; ++j)
        acc[i][j] = __builtin_amdgcn_mfma_f32_16x16x32_bf16(af[i], bfr[j], acc[i][j], 0, 0, 0);
    __syncthreads();
  }

  #pragma unroll
  for (int i = 0; i < 2; ++i) {
    #pragma unroll
    for (int j = 0; j < 4; ++j) {
      int t = wn * 64 + j * 16 + (lane & 15);
      #pragma unroll
      for (int rr = 0; rr < 4; ++rr) {
        int b = b0 + wm * 32 + i * 16 + (lane >> 4) * 4 + rr;
        size_t off = ((size_t)(n * 512 + (b >> 3))) * 1024 + (size_t)(b & 7) * 128 + t;
        A2[off] = (bf16)acc[i][j][rr];
      }
    }
  }
}

// ---------------------------------------------------------------------------
// GEMM2 high-occupancy: x[4096][8192] = A2 @ PW^T + pb.
// Tile 256x256, 1024 threads = 16 waves (4M x 4N), wave = 64x64 (acc 64 VGPR
// -> <=128 total -> 4 waves/SIMD). 32 sub-tiles BK=32, 4 LDS buffers (128KB),
// stage 3 ahead (1 A-unit + 1 B-unit per sub-tile), counted vmcnt(4).
template<bool ZB>
__global__ __launch_bounds__(1024, 4) void gemm2v_kernel(
    const bf16* __restrict__ A2, const bf16* __restrict__ PW,
    const float* __restrict__ pb, void* __restrict__ xoutp)
{
  __shared__ __align__(16) bf16 As[4][8192];  // [buf][256 rows x 32 k] 16KB
  __shared__ __align__(16) bf16 Bs[4][8192];

  const int tid  = threadIdx.x;
  const int w    = tid >> 6;
  const int lane = tid & 63;
  const int wm   = w >> 2;       // 0..3
  const int wn   = w & 3;        // 0..3

  const int bid   = blockIdx.x;          // 0..511
  const int x     = bid & 7;
  const int local = bid >> 3;            // 0..63
  const int mt    = local & 15;
  const int nt    = x * 4 + (local >> 4);
  const int m0    = mt * 256;
  const int n0    = nt * 256;

  // staging: thread tid -> row tid>>2 (0..255), chunk (tid&3)^hsw(row);
  // one 16B gload per operand per sub-tile (1024 thr x 16B = 16KB = sub-tile).
  const int rS = tid >> 2;
  const int cS = (tid & 3) ^ hsw(rS);
  const char* aG = (const char*)A2 + (size_t)(m0 + rS) * 2048 + cS * 16;
  const char* bG = (const char*)PW + (size_t)(n0 + rS) * 2048 + cS * 16;

  #define STAGE(t) { gload_lds16(aG + (size_t)(t) * 64, (char*)As[(t) & 3] + tid * 16); \
                     gload_lds16(bG + (size_t)(t) * 64, (char*)Bs[(t) & 3] + tid * 16); }

  // prologue: sub-tiles 0,1,2 staged (6 loads); wait tile 0 (4 in flight)
  STAGE(0); STAGE(1); STAGE(2);
  asm volatile("s_waitcnt vmcnt(4)" ::: "memory");
  __builtin_amdgcn_s_barrier();
  __builtin_amdgcn_sched_barrier(0);

  f32x4 acc[4][4] = {};
  const int fr = lane & 15;
  const int g  = lane >> 4;

  #pragma unroll 1
  for (int t = 0; t < 32; ++t) {
    if (t < 29) STAGE(t + 3);

    const char* pA = (const char*)As[t & 3];
    const char* pB = (const char*)Bs[t & 3];
    bf16x8 a[4], b[4];
    #pragma unroll
    for (int i = 0; i < 4; ++i) {
      int r = wm * 64 + i * 16 + fr;
      a[i] = *(const bf16x8*)(pA + r * 64 + ((g ^ hsw(r)) << 4));
    }
    #pragma unroll
    for (int j = 0; j < 4; ++j) {
      int r = wn * 64 + j * 16 + fr;
      b[j] = *(const bf16x8*)(pB + r * 64 + ((g ^ hsw(r)) << 4));
    }
    #pragma unroll
    for (int i = 0; i < 4; ++i)
      #pragma unroll
      for (int j = 0; j < 4; ++j)
        acc[i][j] = __builtin_amdgcn_mfma_f32_16x16x32_bf16(a[i], b[j], acc[i][j], 0, 0, 0);

    if (t < 31) {
      asm volatile("s_waitcnt lgkmcnt(0)" ::: "memory");
      if (t < 29)       { asm volatile("s_waitcnt vmcnt(4)" ::: "memory"); }
      else if (t == 29) { asm volatile("s_waitcnt vmcnt(2)" ::: "memory"); }
      else              { asm volatile("s_waitcnt vmcnt(0)" ::: "memory"); }
      __builtin_amdgcn_s_barrier();
      __builtin_amdgcn_sched_barrier(0);
    }
    }
  #undef STAGE

  // epilogue: x = acc + pb -> bf16 ws (or f32 d_out)
  #pragma unroll
  for (int i = 0; i < 4; ++i) {
    #pragma unroll
    for (int j = 0; j < 4; ++j) {
      int nn = n0 + wn * 64 + j * 16 + fr;
      float pbn = pb[nn];
      #pragma unroll
      for (int r = 0; r < 4; ++r) {
        int mm = m0 + wm * 64 + i * 16 + g * 4 + r;
        size_t off = (size_t)mm * 8192 + nn;
        float val = acc[i][j][r] + pbn;
        if (ZB) ((bf16*)xoutp)[off] = (bf16)val;
        else    ((float*)xoutp)[off] = val;
      }
    }
  }
}

// ---------------------------------------------------------------------------
// LN over 1024-wide rows: x = z + v(residual); ddof=1, eps outside sqrt.
// Fills attns region (first 128 blocks) too.
template<bool ZB>
__global__ __launch_bounds__(256) void ln_kernel(
    const void* zin, const float* __restrict__ vres,
    const float* __restrict__ gamma, const float* __restrict__ beta,
    float* outp)
{
  __shared__ float red[16];
  const int row = blockIdx.x;
  const int tid = threadIdx.x;
  if (row < 128) outp[(size_t)33554432 + row * 256 + tid] = 1.0f;
  const size_t base = (size_t)row * 1024 + tid * 4;

  float4 rv = *(const float4*)&vres[base];
  float4 x;
  if (ZB) {
    bf16x4 zb4 = *(const bf16x4*)((const bf16*)zin + base);
    x.x = (float)zb4[0] + rv.x; x.y = (float)zb4[1] + rv.y;
    x.z = (float)zb4[2] + rv.z; x.w = (float)zb4[3] + rv.w;
  } else {
    float4 zf = *(const float4*)((const float*)zin + base);
    x.x = zf.x + rv.x; x.y = zf.y + rv.y; x.z = zf.z + rv.z; x.w = zf.w + rv.w;
  }

  float s  = x.x + x.y + x.z + x.w;
  float ss = x.x * x.x + x.y * x.y + x.z * x.z + x.w * x.w;
  #pragma unroll
  for (int m = 32; m >= 1; m >>= 1) {
    s  += __shfl_xor(s,  m, 64);
    ss += __shfl_xor(ss, m, 64);
  }
  const int wave = tid >> 6, lane = tid & 63;
  if (lane == 0) { red[wave] = s; red[wave + 8] = ss; }
  __syncthreads();
  float S  = red[0] + red[1] + red[2] + red[3];
  float SS = red[8] + red[9] + red[10] + red[11];
  float mu  = S * (1.0f / 1024.0f);
  float var = (SS - 1024.0f * mu * mu) * (1.0f / 1023.0f);
  var = var < 0.0f ? 0.0f : var;
  float rs = 1.0f / (sqrtf(var) + 1e-3f);
  float4 gmv = *(const float4*)&gamma[tid * 4];
  float4 be  = *(const float4*)&beta[tid * 4];
  float4 y;
  y.x = (x.x - mu) * rs * gmv.x + be.x;
  y.y = (x.y - mu) * rs * gmv.y + be.y;
  y.z = (x.z - mu) * rs * gmv.z + be.z;
  y.w = (x.w - mu) * rs * gmv.w + be.w;
  *(float4*)&outp[base] = y;
}

// ---------------------------------------------------------------------------
extern "C" void kernel_launch(void* const* d_in, const int* in_sizes, int n_in,
                              void* d_out, int out_size, void* d_ws, size_t ws_size,
                              hipStream_t stream) {
  const float* v     = (const float*)d_in[2];
  const float* wvs   = (const float*)d_in[5];
  const float* pw    = (const float*)d_in[6];
  const float* pb    = (const float*)d_in[7];
  const float* gamma = (const float*)d_in[8];
  const float* beta  = (const float*)d_in[9];
  float* out = (float*)d_out;

  // ws: PW bf16 16M | WvT bf16 2M | A2 bf16 8M | x bf16 64M
  const size_t OFF_WVT = 16777216;
  const size_t OFF_A2  = OFF_WVT + 2097152;
  const size_t OFF_X   = OFF_A2 + 8388608;
  const size_t NEED_ZB = OFF_X + 67108864;

  bf16* PWb = (bf16*)d_ws;
  bf16* WvT = (bf16*)((char*)d_ws + OFF_WVT);
  bf16* A2  = (bf16*)((char*)d_ws + OFF_A2);
  const bool zb = (ws_size >= NEED_ZB);
  void* xbuf = zb ? (void*)((char*)d_ws + OFF_X) : (void*)out;

  hipLaunchKernelGGL(prep_kernel, dim3(12288), dim3(256), 0, stream, pw, PWb, wvs, WvT);
  hipLaunchKernelGGL(gemm1_kernel, dim3(64, 8), dim3(256), 0, stream, v, WvT, A2);
  if (zb) {
    hipLaunchKernelGGL((gemm2v_kernel<true>),  dim3(512), dim3(1024), 0, stream, A2, PWb, pb, xbuf);
    hipLaunchKernelGGL((ln_kernel<true>),      dim3(32768), dim3(256), 0, stream, xbuf, v, gamma, beta, out);
  } else {
    hipLaunchKernelGGL((gemm2v_kernel<false>), dim3(512), dim3(1024), 0, stream, A2, PWb, pb, xbuf);
    hipLaunchKernelGGL((ln_kernel<false>),     dim3(32768), dim3(256), 0, stream, xbuf, v, gamma, beta, out);
  }
}